// Round 2
// baseline (2530.851 us; speedup 1.0000x reference)
//
#include <hip/hip_runtime.h>

#define BB 4
#define NN 2048
#define DD 256
#define HH 8
#define RR 64
#define DHH 32
#define KSP 32
#define ROWS (BB*NN)   // 8192
#define NBH (BB*HH)    // 32

// ---------------- K1: h = (x @ U_np) @ V_np + b_np ----------------
__global__ __launch_bounds__(64) void k_node_proj(
    const float* __restrict__ x, const float* __restrict__ U,
    const float* __restrict__ V, const float* __restrict__ bias,
    float* __restrict__ h)
{
    const int row = blockIdx.x, lane = threadIdx.x;
    __shared__ float xs[DD];
    __shared__ float ts[RR];
    const float* xr = x + (size_t)row * DD;
    { float4 t4 = ((const float4*)xr)[lane];
      xs[lane*4]=t4.x; xs[lane*4+1]=t4.y; xs[lane*4+2]=t4.z; xs[lane*4+3]=t4.w; }
    __syncthreads();
    float t = 0.f;
    for (int d = 0; d < DD; ++d) t = fmaf(xs[d], U[d*RR + lane], t);
    ts[lane] = t;
    __syncthreads();
    float a[4];
    #pragma unroll
    for (int j = 0; j < 4; ++j) a[j] = bias[lane + 64*j];
    for (int r = 0; r < RR; ++r) {
        float tv = ts[r];
        const float* Vr = V + r*DD + lane;
        #pragma unroll
        for (int j = 0; j < 4; ++j) a[j] = fmaf(tv, Vr[64*j], a[j]);
    }
    float* hr = h + (size_t)row * DD;
    #pragma unroll
    for (int j = 0; j < 4; ++j) hr[lane + 64*j] = a[j];
}

// ---------------- K2: q,k,v = lowrank(h) in [BH][N][DH] layout ----------------
__global__ __launch_bounds__(64) void k_qkv(
    const float* __restrict__ h,
    const float* __restrict__ Uq, const float* __restrict__ Vq,
    const float* __restrict__ Uk, const float* __restrict__ Vk,
    const float* __restrict__ Uv, const float* __restrict__ Vv,
    float* __restrict__ q, float* __restrict__ k, float* __restrict__ v)
{
    const int row = blockIdx.x, lane = threadIdx.x;
    __shared__ float hs[DD];
    __shared__ float tq[RR], tk[RR], tvv[RR];
    const float* hr = h + (size_t)row * DD;
    { float4 t4 = ((const float4*)hr)[lane];
      hs[lane*4]=t4.x; hs[lane*4+1]=t4.y; hs[lane*4+2]=t4.z; hs[lane*4+3]=t4.w; }
    __syncthreads();
    float aq=0.f, ak=0.f, av=0.f;
    for (int d = 0; d < DD; ++d) {
        float hv = hs[d];
        aq = fmaf(hv, Uq[d*RR + lane], aq);
        ak = fmaf(hv, Uk[d*RR + lane], ak);
        av = fmaf(hv, Uv[d*RR + lane], av);
    }
    tq[lane]=aq; tk[lane]=ak; tvv[lane]=av;
    __syncthreads();
    float oq[4], ok[4], ov[4];
    #pragma unroll
    for (int j = 0; j < 4; ++j) { oq[j]=0.f; ok[j]=0.f; ov[j]=0.f; }
    for (int r = 0; r < RR; ++r) {
        float sq=tq[r], sk=tk[r], sv=tvv[r];
        const int base = r*DD + lane;
        #pragma unroll
        for (int j = 0; j < 4; ++j) {
            oq[j] = fmaf(sq, Vq[base + 64*j], oq[j]);
            ok[j] = fmaf(sk, Vk[base + 64*j], ok[j]);
            ov[j] = fmaf(sv, Vv[base + 64*j], ov[j]);
        }
    }
    const int b_ = row >> 11, n_ = row & (NN-1);
    #pragma unroll
    for (int j = 0; j < 4; ++j) {
        int c = lane + 64*j;
        int hd = c >> 5, dd = c & 31;
        size_t idx = ((size_t)(b_*HH + hd)*NN + n_)*DHH + dd;
        q[idx] = oq[j]; k[idx] = ok[j]; v[idx] = ov[j];
    }
}

// ---------------- K3: sparse top-32 attention, one wave per query row ----------------
__global__ __launch_bounds__(64) void k_attn(
    const float* __restrict__ q, const float* __restrict__ kx,
    const float* __restrict__ vx, float* __restrict__ o)
{
    const int row = blockIdx.x;          // 0..BH*N-1
    const int bh = row >> 11, n = row & (NN-1);
    const int lane = threadIdx.x;
    const float* qp = q  + ((size_t)bh*NN + n)*DHH;
    const float* kp = kx + (size_t)bh*NN*DHH;
    const float* vp = vx + (size_t)bh*NN*DHH;

    __shared__ float qs[DHH];
    if (lane < DHH) qs[lane] = qp[lane];
    __syncthreads();
    float qr[DHH];
    #pragma unroll
    for (int d = 0; d < DHH; ++d) qr[d] = qs[d];

    const float scale = 0.17677669529663687f;  // 1/sqrt(32)
    unsigned u[32];
    float smax = -3.4e38f;
    #pragma unroll
    for (int i = 0; i < 32; ++i) {
        const float* kr = kp + (size_t)(i*64 + lane)*DHH;
        float acc = 0.f;
        #pragma unroll
        for (int d = 0; d < DHH; d += 4) {
            float4 kv = *(const float4*)(kr + d);
            acc = fmaf(qr[d],   kv.x, acc);
            acc = fmaf(qr[d+1], kv.y, acc);
            acc = fmaf(qr[d+2], kv.z, acc);
            acc = fmaf(qr[d+3], kv.w, acc);
        }
        float s = acc * scale;
        smax = fmaxf(smax, s);
        unsigned bb = __float_as_uint(s);
        u[i] = (bb & 0x80000000u) ? ~bb : (bb | 0x80000000u);
    }
    #pragma unroll
    for (int m = 1; m < 64; m <<= 1) smax = fmaxf(smax, __shfl_xor(smax, m, 64));

    // exact 32nd-largest via bitwise binary search on monotone-mapped uints
    unsigned thr = 0u;
    for (int bit = 31; bit >= 0; --bit) {
        unsigned cand = thr | (1u << bit);
        int cnt = 0;
        #pragma unroll
        for (int i = 0; i < 32; ++i) cnt += (u[i] >= cand) ? 1 : 0;
        #pragma unroll
        for (int m = 1; m < 64; m <<= 1) cnt += __shfl_xor(cnt, m, 64);
        if (cnt >= KSP) thr = cand;
    }

    // pass 2: masked softmax + sparse PV
    float acc[DHH];
    #pragma unroll
    for (int d = 0; d < DHH; ++d) acc[d] = 0.f;
    float sw = 0.f;
    #pragma unroll
    for (int i = 0; i < 32; ++i) {
        if (u[i] >= thr) {
            unsigned bb = u[i];
            float s = __uint_as_float((bb & 0x80000000u) ? (bb ^ 0x80000000u) : ~bb);
            float w = __expf(s - smax);
            sw += w;
            const float* vr = vp + (size_t)(i*64 + lane)*DHH;
            #pragma unroll
            for (int d = 0; d < DHH; d += 4) {
                float4 vv = *(const float4*)(vr + d);
                acc[d]   = fmaf(w, vv.x, acc[d]);
                acc[d+1] = fmaf(w, vv.y, acc[d+1]);
                acc[d+2] = fmaf(w, vv.z, acc[d+2]);
                acc[d+3] = fmaf(w, vv.w, acc[d+3]);
            }
        }
    }
    #pragma unroll
    for (int m = 1; m < 64; m <<= 1) sw += __shfl_xor(sw, m, 64);

    __shared__ float as_[64][33];
    #pragma unroll
    for (int d = 0; d < DHH; ++d) as_[lane][d] = acc[d];
    __syncthreads();
    if (lane < DHH) {
        float t = 0.f;
        for (int l = 0; l < 64; ++l) t += as_[l][lane];
        const int b_ = bh >> 3, hd = bh & 7;
        o[((size_t)(b_*NN + n))*DD + hd*DHH + lane] = t / sw;
    }
}

// ---------------- K4: out_pre = lowrank(lowrank(o, Uo,Vo,bo), Uop,Vop,bop) ----------------
__global__ __launch_bounds__(64) void k_out_proj(
    const float* __restrict__ o,
    const float* __restrict__ Uo,  const float* __restrict__ Vo,  const float* __restrict__ bo,
    const float* __restrict__ Uop, const float* __restrict__ Vop, const float* __restrict__ bop,
    float* __restrict__ outp)
{
    const int row = blockIdx.x, lane = threadIdx.x;
    __shared__ float buf[DD];
    __shared__ float ts[RR];
    const float* orow = o + (size_t)row * DD;
    { float4 t4 = ((const float4*)orow)[lane];
      buf[lane*4]=t4.x; buf[lane*4+1]=t4.y; buf[lane*4+2]=t4.z; buf[lane*4+3]=t4.w; }
    __syncthreads();
    // stage 1
    float t = 0.f;
    for (int d = 0; d < DD; ++d) t = fmaf(buf[d], Uo[d*RR + lane], t);
    ts[lane] = t;
    __syncthreads();
    float a[4];
    #pragma unroll
    for (int j = 0; j < 4; ++j) a[j] = bo[lane + 64*j];
    for (int r = 0; r < RR; ++r) {
        float tv = ts[r];
        #pragma unroll
        for (int j = 0; j < 4; ++j) a[j] = fmaf(tv, Vo[r*DD + lane + 64*j], a[j]);
    }
    __syncthreads();
    #pragma unroll
    for (int j = 0; j < 4; ++j) buf[lane + 64*j] = a[j];
    __syncthreads();
    // stage 2
    float t2 = 0.f;
    for (int d = 0; d < DD; ++d) t2 = fmaf(buf[d], Uop[d*RR + lane], t2);
    __syncthreads();
    ts[lane] = t2;
    __syncthreads();
    float c[4];
    #pragma unroll
    for (int j = 0; j < 4; ++j) c[j] = bop[lane + 64*j];
    for (int r = 0; r < RR; ++r) {
        float tv = ts[r];
        #pragma unroll
        for (int j = 0; j < 4; ++j) c[j] = fmaf(tv, Vop[r*DD + lane + 64*j], c[j]);
    }
    float* orow_out = outp + (size_t)row * DD;
    #pragma unroll
    for (int j = 0; j < 4; ++j) orow_out[lane + 64*j] = c[j];
}

// ---------------- K5: BN batch stats per channel ----------------
__global__ __launch_bounds__(256) void k_bnstats(
    const float* __restrict__ outp, float* __restrict__ stats,
    const float* __restrict__ gamma, const float* __restrict__ beta)
{
    const int c = blockIdx.x, t = threadIdx.x;
    float s = 0.f, s2 = 0.f;
    for (int r = t; r < ROWS; r += 256) {
        float v = outp[(size_t)r*DD + c];
        s += v; s2 += v*v;
    }
    __shared__ float rs[256], rs2[256];
    rs[t] = s; rs2[t] = s2;
    __syncthreads();
    for (int step = 128; step; step >>= 1) {
        if (t < step) { rs[t] += rs[t+step]; rs2[t] += rs2[t+step]; }
        __syncthreads();
    }
    if (t == 0) {
        float mean = rs[0] * (1.0f/ROWS);
        float var  = rs2[0] * (1.0f/ROWS) - mean*mean;
        float inv  = rsqrtf(var + 1e-5f);
        float g = gamma[c], be = beta[c];
        stats[c]      = g * inv;
        stats[DD + c] = be - mean * g * inv;
    }
}

// ---------------- K6: apply BN (fp32 out) ----------------
__global__ __launch_bounds__(256) void k_bnapply(
    const float* __restrict__ outp, const float* __restrict__ stats,
    float* __restrict__ out)
{
    const size_t idx = (size_t)blockIdx.x * 256 + threadIdx.x;
    const int c = (int)(idx & (DD-1));
    out[idx] = outp[idx] * stats[c] + stats[DD + c];
}

extern "C" void kernel_launch(void* const* d_in, const int* in_sizes, int n_in,
                              void* d_out, int out_size, void* d_ws, size_t ws_size,
                              hipStream_t stream)
{
    (void)in_sizes; (void)n_in; (void)out_size; (void)ws_size;
    const float* x    = (const float*)d_in[0];
    const float* U_np = (const float*)d_in[1];
    const float* V_np = (const float*)d_in[2];
    const float* b_np = (const float*)d_in[3];
    const float* U_q  = (const float*)d_in[4];
    const float* V_q  = (const float*)d_in[5];
    const float* U_k  = (const float*)d_in[6];
    const float* V_k  = (const float*)d_in[7];
    const float* U_v  = (const float*)d_in[8];
    const float* V_v  = (const float*)d_in[9];
    const float* U_o  = (const float*)d_in[10];
    const float* V_o  = (const float*)d_in[11];
    const float* b_o  = (const float*)d_in[12];
    const float* U_op = (const float*)d_in[13];
    const float* V_op = (const float*)d_in[14];
    const float* b_op = (const float*)d_in[15];
    const float* gamma= (const float*)d_in[16];
    const float* beta = (const float*)d_in[17];

    float* ws  = (float*)d_ws;
    float* out = (float*)d_out;
    const size_t BUF = (size_t)ROWS * DD;     // 2,097,152 floats = 8 MB

    // d_out doubles as staging (h, then o); ws holds q,k,v (+outp, stats reuse)
    float* h    = out;        // written K1, read K2, dead after
    float* q    = ws;
    float* k    = ws + BUF;
    float* v    = ws + 2*BUF;
    float* o    = out;        // written K3, read K4 (h dead)
    float* outp = q;          // written K4, read K5/K6 (q dead)
    float* stats= k;          // 512 floats (k dead)

    k_node_proj<<<ROWS, 64, 0, stream>>>(x, U_np, V_np, b_np, h);
    k_qkv<<<ROWS, 64, 0, stream>>>(h, U_q, V_q, U_k, V_k, U_v, V_v, q, k, v);
    k_attn<<<NBH*NN, 64, 0, stream>>>(q, k, v, o);
    k_out_proj<<<ROWS, 64, 0, stream>>>(o, U_o, V_o, b_o, U_op, V_op, b_op, outp);
    k_bnstats<<<DD, 256, 0, stream>>>(outp, stats, gamma, beta);
    k_bnapply<<<ROWS, 256, 0, stream>>>(outp, stats, out);
}

// Round 3
// 1379.846 us; speedup vs baseline: 1.8342x; 1.8342x over previous
//
#include <hip/hip_runtime.h>

#define BB 4
#define NN 2048
#define DD 256
#define HH 8
#define RR 64
#define DHH 32
#define KSP 32
#define ROWS (BB*NN)   // 8192
#define NEG_INF (-3.0e38f)

// ---------------- K1: h = (x @ U_np) @ V_np + b_np ----------------
__global__ __launch_bounds__(64) void k_node_proj(
    const float* __restrict__ x, const float* __restrict__ U,
    const float* __restrict__ V, const float* __restrict__ bias,
    float* __restrict__ h)
{
    const int row = blockIdx.x, lane = threadIdx.x;
    __shared__ float xs[DD];
    __shared__ float ts[RR];
    const float* xr = x + (size_t)row * DD;
    { float4 t4 = ((const float4*)xr)[lane];
      xs[lane*4]=t4.x; xs[lane*4+1]=t4.y; xs[lane*4+2]=t4.z; xs[lane*4+3]=t4.w; }
    __syncthreads();
    float t = 0.f;
    for (int d = 0; d < DD; ++d) t = fmaf(xs[d], U[d*RR + lane], t);
    ts[lane] = t;
    __syncthreads();
    float a[4];
    #pragma unroll
    for (int j = 0; j < 4; ++j) a[j] = bias[lane + 64*j];
    for (int r = 0; r < RR; ++r) {
        float tv = ts[r];
        const float* Vr = V + r*DD + lane;
        #pragma unroll
        for (int j = 0; j < 4; ++j) a[j] = fmaf(tv, Vr[64*j], a[j]);
    }
    float* hr = h + (size_t)row * DD;
    #pragma unroll
    for (int j = 0; j < 4; ++j) hr[lane + 64*j] = a[j];
}

// ---------------- K2: q,k,v = lowrank(h), kept in [B,N,D] layout ----------------
__global__ __launch_bounds__(64) void k_qkv(
    const float* __restrict__ h,
    const float* __restrict__ Uq, const float* __restrict__ Vq,
    const float* __restrict__ Uk, const float* __restrict__ Vk,
    const float* __restrict__ Uv, const float* __restrict__ Vv,
    float* __restrict__ q, float* __restrict__ k, float* __restrict__ v)
{
    const int row = blockIdx.x, lane = threadIdx.x;
    __shared__ float hs[DD];
    __shared__ float tq[RR], tk[RR], tvv[RR];
    const float* hr = h + (size_t)row * DD;
    { float4 t4 = ((const float4*)hr)[lane];
      hs[lane*4]=t4.x; hs[lane*4+1]=t4.y; hs[lane*4+2]=t4.z; hs[lane*4+3]=t4.w; }
    __syncthreads();
    float aq=0.f, ak=0.f, av=0.f;
    for (int d = 0; d < DD; ++d) {
        float hv = hs[d];
        aq = fmaf(hv, Uq[d*RR + lane], aq);
        ak = fmaf(hv, Uk[d*RR + lane], ak);
        av = fmaf(hv, Uv[d*RR + lane], av);
    }
    tq[lane]=aq; tk[lane]=ak; tvv[lane]=av;
    __syncthreads();
    float oq[4], ok[4], ov[4];
    #pragma unroll
    for (int j = 0; j < 4; ++j) { oq[j]=0.f; ok[j]=0.f; ov[j]=0.f; }
    for (int r = 0; r < RR; ++r) {
        float sq=tq[r], sk=tk[r], sv=tvv[r];
        const int base = r*DD + lane;
        #pragma unroll
        for (int j = 0; j < 4; ++j) {
            oq[j] = fmaf(sq, Vq[base + 64*j], oq[j]);
            ok[j] = fmaf(sk, Vk[base + 64*j], ok[j]);
            ov[j] = fmaf(sv, Vv[base + 64*j], ov[j]);
        }
    }
    float* qr = q + (size_t)row * DD;
    float* kr = k + (size_t)row * DD;
    float* vr = v + (size_t)row * DD;
    #pragma unroll
    for (int j = 0; j < 4; ++j) {
        qr[lane + 64*j] = oq[j];
        kr[lane + 64*j] = ok[j];
        vr[lane + 64*j] = ov[j];
    }
}

// dot over 32 dims; IDENTICAL rounding order in both phases (4 partial sums)
__device__ __forceinline__ float dot32(const float4* qa, const float* kr) {
    float s0=0.f, s1=0.f, s2=0.f, s3=0.f;
    #pragma unroll
    for (int i = 0; i < 8; ++i) {
        float4 kv = ((const float4*)kr)[i];   // wave-uniform broadcast load
        s0 = fmaf(qa[i].x, kv.x, s0);
        s1 = fmaf(qa[i].y, kv.y, s1);
        s2 = fmaf(qa[i].z, kv.z, s2);
        s3 = fmaf(qa[i].w, kv.w, s3);
    }
    return (s0+s1)+(s2+s3);
}

// ---------------- K3: sparse top-32 attention, lane = query ----------------
// block = 256 threads = 4 waves; block owns 64 queries (one per lane),
// wave w scans keys [512w, 512w+512). Exact top-32 via per-lane sorted
// register list + 4-way LDS merge. Phase 2 recomputes scores (same rounding)
// and applies softmax+PV with s >= thr (exact tie semantics).
__global__ __launch_bounds__(256) void k_attn(
    const float* __restrict__ q, const float* __restrict__ kx,
    const float* __restrict__ vx, float* __restrict__ o)
{
    __shared__ float tl[4][DHH][64];   // 32 KB: top-32 lists, then acc reuse
    __shared__ float swl[4][64];
    const int lane = threadIdx.x & 63;
    const int wv   = threadIdx.x >> 6;
    const int blk  = blockIdx.x;
    const int tile = blk & 31;
    const int head = (blk >> 5) & 7;
    const int b    = blk >> 8;
    const int n    = tile*64 + lane;

    const float* qp    = q  + ((size_t)(b*NN + n))*DD + head*DHH;
    const float* kbase = kx + (size_t)b*NN*DD + head*DHH;
    const float* vbase = vx + (size_t)b*NN*DD + head*DHH;
    const float scale = 0.17677669529663687f;  // 1/sqrt(32)

    float4 qa[8];
    #pragma unroll
    for (int i = 0; i < 8; ++i) qa[i] = ((const float4*)qp)[i];

    // ---- phase 1: per-lane running top-32 (sorted ascending) ----
    float t[32];
    #pragma unroll
    for (int i = 0; i < 32; ++i) t[i] = NEG_INF;

    const int j0 = wv*512, j1 = j0 + 512;
    #pragma unroll 2
    for (int j = j0; j < j1; ++j) {
        float s = dot32(qa, kbase + (size_t)j*DD) * scale;
        if (__any(s > t[0])) {
            float sv = (s > t[0]) ? s : NEG_INF;
            #pragma unroll
            for (int i = 0; i < 31; ++i) t[i] = fmaxf(fminf(t[i+1], sv), t[i]);
            t[31] = fmaxf(t[31], sv);
        }
    }
    #pragma unroll
    for (int i = 0; i < 32; ++i) tl[wv][i][lane] = t[i];
    __syncthreads();

    // ---- merge 4 sorted lists: march 32 picks -> global max + 32nd ----
    int i0=31, i1=31, i2=31, i3=31;
    float m = NEG_INF, thr = NEG_INF;
    for (int p = 0; p < 32; ++p) {
        float v0 = tl[0][i0][lane];
        float v1 = tl[1][i1][lane];
        float v2 = tl[2][i2][lane];
        float v3 = tl[3][i3][lane];
        float vm = fmaxf(fmaxf(v0,v1), fmaxf(v2,v3));
        if (p == 0) m = vm;
        thr = vm;
        if      (vm == v0) --i0;
        else if (vm == v1) --i1;
        else if (vm == v2) --i2;
        else               --i3;
    }
    __syncthreads();   // everyone done reading tl before acc reuse

    // ---- phase 2: recompute scores, masked softmax + PV ----
    float acc[32];
    #pragma unroll
    for (int d = 0; d < 32; ++d) acc[d] = 0.f;
    float sw = 0.f;
    #pragma unroll 2
    for (int j = j0; j < j1; ++j) {
        float s = dot32(qa, kbase + (size_t)j*DD) * scale;
        bool sel = (s >= thr);
        if (__any(sel)) {
            float w = sel ? __expf(s - m) : 0.f;
            sw += w;
            const float* vr = vbase + (size_t)j*DD;
            #pragma unroll
            for (int i = 0; i < 8; ++i) {
                float4 vvv = ((const float4*)vr)[i];   // wave-uniform broadcast
                acc[4*i]   = fmaf(w, vvv.x, acc[4*i]);
                acc[4*i+1] = fmaf(w, vvv.y, acc[4*i+1]);
                acc[4*i+2] = fmaf(w, vvv.z, acc[4*i+2]);
                acc[4*i+3] = fmaf(w, vvv.w, acc[4*i+3]);
            }
        }
    }
    #pragma unroll
    for (int d = 0; d < 32; ++d) tl[wv][d][lane] = acc[d];
    swl[wv][lane] = sw;
    __syncthreads();

    // ---- combine across waves: wave wv writes dims [8wv, 8wv+8) ----
    float swsum = swl[0][lane] + swl[1][lane] + swl[2][lane] + swl[3][lane];
    float inv = 1.0f / swsum;
    float* orow = o + ((size_t)(b*NN + n))*DD + head*DHH;
    #pragma unroll
    for (int dd = 0; dd < 8; ++dd) {
        int d = 8*wv + dd;
        float sv = tl[0][d][lane] + tl[1][d][lane] + tl[2][d][lane] + tl[3][d][lane];
        orow[d] = sv * inv;
    }
}

// ---------------- K4: out_pre = lowrank(lowrank(o)) ----------------
__global__ __launch_bounds__(64) void k_out_proj(
    const float* __restrict__ o,
    const float* __restrict__ Uo,  const float* __restrict__ Vo,  const float* __restrict__ bo,
    const float* __restrict__ Uop, const float* __restrict__ Vop, const float* __restrict__ bop,
    float* __restrict__ outp)
{
    const int row = blockIdx.x, lane = threadIdx.x;
    __shared__ float buf[DD];
    __shared__ float ts[RR];
    const float* orow = o + (size_t)row * DD;
    { float4 t4 = ((const float4*)orow)[lane];
      buf[lane*4]=t4.x; buf[lane*4+1]=t4.y; buf[lane*4+2]=t4.z; buf[lane*4+3]=t4.w; }
    __syncthreads();
    float t = 0.f;
    for (int d = 0; d < DD; ++d) t = fmaf(buf[d], Uo[d*RR + lane], t);
    ts[lane] = t;
    __syncthreads();
    float a[4];
    #pragma unroll
    for (int j = 0; j < 4; ++j) a[j] = bo[lane + 64*j];
    for (int r = 0; r < RR; ++r) {
        float tv = ts[r];
        #pragma unroll
        for (int j = 0; j < 4; ++j) a[j] = fmaf(tv, Vo[r*DD + lane + 64*j], a[j]);
    }
    __syncthreads();
    #pragma unroll
    for (int j = 0; j < 4; ++j) buf[lane + 64*j] = a[j];
    __syncthreads();
    float t2 = 0.f;
    for (int d = 0; d < DD; ++d) t2 = fmaf(buf[d], Uop[d*RR + lane], t2);
    __syncthreads();
    ts[lane] = t2;
    __syncthreads();
    float c[4];
    #pragma unroll
    for (int j = 0; j < 4; ++j) c[j] = bop[lane + 64*j];
    for (int r = 0; r < RR; ++r) {
        float tv = ts[r];
        #pragma unroll
        for (int j = 0; j < 4; ++j) c[j] = fmaf(tv, Vop[r*DD + lane + 64*j], c[j]);
    }
    float* orow_out = outp + (size_t)row * DD;
    #pragma unroll
    for (int j = 0; j < 4; ++j) orow_out[lane + 64*j] = c[j];
}

// ---------------- K5: BN batch stats per channel ----------------
__global__ __launch_bounds__(256) void k_bnstats(
    const float* __restrict__ outp, float* __restrict__ stats,
    const float* __restrict__ gamma, const float* __restrict__ beta)
{
    const int c = blockIdx.x, t = threadIdx.x;
    float s = 0.f, s2 = 0.f;
    for (int r = t; r < ROWS; r += 256) {
        float v = outp[(size_t)r*DD + c];
        s += v; s2 += v*v;
    }
    __shared__ float rs[256], rs2[256];
    rs[t] = s; rs2[t] = s2;
    __syncthreads();
    for (int step = 128; step; step >>= 1) {
        if (t < step) { rs[t] += rs[t+step]; rs2[t] += rs2[t+step]; }
        __syncthreads();
    }
    if (t == 0) {
        float mean = rs[0] * (1.0f/ROWS);
        float var  = rs2[0] * (1.0f/ROWS) - mean*mean;
        float inv  = rsqrtf(var + 1e-5f);
        float g = gamma[c], be = beta[c];
        stats[c]      = g * inv;
        stats[DD + c] = be - mean * g * inv;
    }
}

// ---------------- K6: apply BN (fp32 out) ----------------
__global__ __launch_bounds__(256) void k_bnapply(
    const float* __restrict__ outp, const float* __restrict__ stats,
    float* __restrict__ out)
{
    const size_t idx = (size_t)blockIdx.x * 256 + threadIdx.x;
    const int c = (int)(idx & (DD-1));
    out[idx] = outp[idx] * stats[c] + stats[DD + c];
}

extern "C" void kernel_launch(void* const* d_in, const int* in_sizes, int n_in,
                              void* d_out, int out_size, void* d_ws, size_t ws_size,
                              hipStream_t stream)
{
    (void)in_sizes; (void)n_in; (void)out_size; (void)ws_size;
    const float* x    = (const float*)d_in[0];
    const float* U_np = (const float*)d_in[1];
    const float* V_np = (const float*)d_in[2];
    const float* b_np = (const float*)d_in[3];
    const float* U_q  = (const float*)d_in[4];
    const float* V_q  = (const float*)d_in[5];
    const float* U_k  = (const float*)d_in[6];
    const float* V_k  = (const float*)d_in[7];
    const float* U_v  = (const float*)d_in[8];
    const float* V_v  = (const float*)d_in[9];
    const float* U_o  = (const float*)d_in[10];
    const float* V_o  = (const float*)d_in[11];
    const float* b_o  = (const float*)d_in[12];
    const float* U_op = (const float*)d_in[13];
    const float* V_op = (const float*)d_in[14];
    const float* b_op = (const float*)d_in[15];
    const float* gamma= (const float*)d_in[16];
    const float* beta = (const float*)d_in[17];

    float* ws  = (float*)d_ws;
    float* out = (float*)d_out;
    const size_t BUF = (size_t)ROWS * DD;     // 2,097,152 floats = 8 MB

    float* h    = out;        // K1 writes, K2 reads, dead after
    float* q    = ws;
    float* k    = ws + BUF;
    float* v    = ws + 2*BUF;
    float* o    = out;        // K3 writes (h dead), K4 reads
    float* outp = q;          // K4 writes (q dead), K5/K6 read
    float* stats= k;          // 512 floats (k dead)

    k_node_proj<<<ROWS, 64, 0, stream>>>(x, U_np, V_np, b_np, h);
    k_qkv<<<ROWS, 64, 0, stream>>>(h, U_q, V_q, U_k, V_k, U_v, V_v, q, k, v);
    k_attn<<<BB*HH*32, 256, 0, stream>>>(q, k, v, o);
    k_out_proj<<<ROWS, 64, 0, stream>>>(o, U_o, V_o, b_o, U_op, V_op, b_op, outp);
    k_bnstats<<<DD, 256, 0, stream>>>(outp, stats, gamma, beta);
    k_bnapply<<<ROWS, 256, 0, stream>>>(outp, stats, out);
}